// Round 7
// baseline (237.376 us; speedup 1.0000x reference)
//
#include <hip/hip_runtime.h>

// Grad3D: out = |dx|+|dy|+|dz|, central differences, zero padding.
// fp32, (4,1,192,224,192) contiguous.
//
// R10: rolling-z LDS ring with counted-vmcnt (never-drain) staging.
// All prior versions alternate stage/compute with a full vmcnt drain
// between (R7/R8: __syncthreads drains vmcnt(0); R4-R6: batch-wait-0).
// Here: 4-slot ring of (14+2)-row y-tiles; per z-step issue stage(z+2)
// (3 global_load_lds per wave), s_waitcnt vmcnt(5) = keep {3 new loads +
// 2 stores} in flight while guaranteeing z+1 landed, raw s_barrier (no
// compiler vmcnt(0)), compute z, barrier. Stage of z+2 lands DURING
// compute of z. Read amplification 16/14 * 18/16 = 1.29x (lowest yet).

constexpr int W = 192, H = 224, D = 192, B = 4;
constexpr int W4     = W / 4;          // 48 float4 per row
constexpr int YT     = 14;             // output rows per y-tile
constexpr int YR     = YT + 2;         // 16 staged rows (y halo)
constexpr int ROWB   = W * 4;          // 768 B
constexpr int SLOTB  = YR * ROWB;      // 12288 B per ring slot
constexpr int SLOTFL = SLOTB / 4;      // 3072 floats
constexpr int SLOTF4 = SLOTB / 16;     // 768 float4
constexpr int ZL     = 16;             // z planes per block
constexpr int NYT    = H / YT;         // 16
constexpr int NZC    = D / ZL;         // 12
constexpr int GRID   = B * NYT * NZC;  // 768 (%8==0; 3 blocks/CU exactly)
constexpr int PERX   = GRID / 8;       // 96 per XCD
constexpr int NTHR   = 256;            // 4 waves
constexpr int NF4    = YT * W4;        // 672 outputs per plane

typedef float f32x4 __attribute__((ext_vector_type(4)));
typedef __attribute__((address_space(3))) unsigned int       lds_u32;
typedef __attribute__((address_space(1))) const unsigned int gbl_u32;

// "memory"-clobbered: fences ds_read hoisting and store sinking across.
#define WAITV(N) asm volatile("s_waitcnt vmcnt(" #N ")" ::: "memory")
#define WAITLG   asm volatile("s_waitcnt lgkmcnt(0)" ::: "memory")
#define BARR     asm volatile("s_barrier" ::: "memory")

__global__ __launch_bounds__(NTHR) void grad3d_kernel(
    const float* __restrict__ in, float* __restrict__ out) {
    __shared__ float s[4 * SLOTFL];    // 4 slots x 16 rows x 192 floats

    // XCD-contiguous swizzle (bijective: GRID % 8 == 0).
    int bid = blockIdx.x;
    int sid = (bid & 7) * PERX + (bid >> 3);
    const int ytile = sid % NYT; sid /= NYT;
    const int zc    = sid % NZC; sid /= NZC;
    const int b     = sid;

    const int tid  = threadIdx.x;
    const int wv   = tid >> 6;         // wave 0..3
    const int lane = tid & 63;
    const int z0   = zc * ZL;
    const int y0   = ytile * YT;
    const bool ybot = (ytile == 0), ytop = (ytile == NYT - 1);

    f32x4* s4 = (f32x4*)s;
    f32x4* out4 = (f32x4*)out;
    const f32x4 zf = {0.f, 0.f, 0.f, 0.f};
    const char* inb = (const char*)in;

    // Pre-zero boundary halo rows (row 0 / row 15) of ALL 4 slots once;
    // staging permanently masks those bytes, so they stay zero.
    if (ybot) for (int i = tid; i < 4 * W4; i += NTHR)
        s4[(i / W4) * SLOTF4 + (i % W4)] = zf;
    if (ytop) for (int i = tid; i < 4 * W4; i += NTHR)
        s4[(i / W4) * SLOTF4 + (YR - 1) * W4 + (i % W4)] = zf;

    // Stage plane q into ring slot (q+4)&3. In-range: 12 x 1KB chunks,
    // 3 per wave (uniform vmcnt count). OOB plane: ds_write zeros.
    auto STAGE = [&](int q) {
        const int sl = (q + 4) & 3;
        if (q < 0 || q >= D) {
            #pragma unroll
            for (int k = 0; k < 3; ++k)
                s4[sl * SLOTF4 + k * NTHR + tid] = zf;
            return;
        }
        const char* gbase = inb + (size_t)((b * D + q) * H + (y0 - 1)) * ROWB;
        char* lbase = (char*)s + sl * SLOTB;
        #pragma unroll
        for (int k = 0; k < 3; ++k) {
            const int c   = 3 * wv + k;             // chunk 0..11
            const int off = (c << 10) + (lane << 4);
            bool ok = true;
            if (ybot && off < ROWB)         ok = false;  // global row -1
            if (ytop && off >= SLOTB - ROWB) ok = false; // global row H
            if (ok)
                __builtin_amdgcn_global_load_lds(
                    (gbl_u32*)(gbase + off),
                    (lds_u32*)(lbase + (c << 10)), 16, 0, 0);
        }
    };

    // ---- prologue: fill ring with planes z0-1, z0, z0+1 ----
    STAGE(z0 - 1);   // zero-filled for zc==0
    STAGE(z0);
    STAGE(z0 + 1);

    for (int t = 0; t < ZL; ++t) {
        const int z = z0 + t;
        const int q = z + 2;
        const bool inr = (q < D);        // q >= 2 always
        STAGE(q);
        // Counted wait: guarantee plane z+1's stage landed; keep this
        // step's 3 loads (+2 oldest stores) in flight. Never 0 mid-march.
        if (t == 0)      WAITV(3);       // no prior stores yet
        else if (inr)    WAITV(5);       // 3 new loads + 2 stores stay
        else             WAITV(2);       // OOB step: drain prev stage
        WAITLG;                          // zero-fill/pre-zero visibility
        BARR;                            // all waves: z-1,z,z+1 resident

        const int szm = (z + 3) & 3, sz = z & 3, szp = (z + 1) & 3;
        #pragma unroll
        for (int it = 0; it < 3; ++it) {
            const int f = it * NTHR + tid;
            if (f < NF4) {
                const int row = f / W4, xv = f % W4;
                const int bf  = (row + 1) * W + 4 * xv;
                f32x4 cc = *(const f32x4*)&s[sz  * SLOTFL + bf];
                f32x4 ym = *(const f32x4*)&s[sz  * SLOTFL + bf - W];
                f32x4 yp = *(const f32x4*)&s[sz  * SLOTFL + bf + W];
                f32x4 zm = *(const f32x4*)&s[szm * SLOTFL + bf];
                f32x4 zp = *(const f32x4*)&s[szp * SLOTFL + bf];

                float l = __shfl_up(cc.w, 1);
                float r = __shfl_down(cc.x, 1);
                if (lane == 0  && xv > 0)      l = s[sz * SLOTFL + bf - 1];
                if (lane == 63 && xv < W4 - 1) r = s[sz * SLOTFL + bf + 4];
                if (xv == 0)      l = 0.f;
                if (xv == W4 - 1) r = 0.f;

                f32x4 o;
                o.x = fabsf((cc.y - l   ) * .5f) + fabsf((yp.x - ym.x) * .5f) + fabsf((zp.x - zm.x) * .5f);
                o.y = fabsf((cc.z - cc.x) * .5f) + fabsf((yp.y - ym.y) * .5f) + fabsf((zp.y - zm.y) * .5f);
                o.z = fabsf((cc.w - cc.y) * .5f) + fabsf((yp.z - ym.z) * .5f) + fabsf((zp.z - zm.z) * .5f);
                o.w = fabsf((r    - cc.z) * .5f) + fabsf((yp.w - ym.w) * .5f) + fabsf((zp.w - zm.w) * .5f);
                __builtin_nontemporal_store(
                    o, out4 + ((size_t)(b * D + z) * H + (y0 + row)) * W4 + xv);
            }
        }
        BARR;   // protect slot (z+3)&3 (read as zm this step) before next stage
    }
}

extern "C" void kernel_launch(void* const* d_in, const int* in_sizes, int n_in,
                              void* d_out, int out_size, void* d_ws, size_t ws_size,
                              hipStream_t stream) {
    const float* x = (const float*)d_in[0];
    float* out     = (float*)d_out;
    grad3d_kernel<<<GRID, NTHR, 0, stream>>>(x, out);
}